// Round 15
// baseline (80.934 us; speedup 1.0000x reference)
//
#include <hip/hip_runtime.h>

typedef float v2f __attribute__((ext_vector_type(2)));

#define IMG 512
#define OUT_N 502
#define NPLANE 48
#define NSTRIP 32            // 16 output rows per strip
#define SROWS 16
#define NBLOCKS (NSTRIP * NPLANE)
#define RPITCH 133           // region pitch (float4 units) in row buffer
#define ROWP (4*RPITCH)      // 532 float4 per buffered V-row
#define C1c 0.0001f
#define C2c 0.0004f
#define FPSCALE 16777216.0f  // 2^24 fixed-point scale for the global sum

// ssim from H-blurred (Bs, Bd, BP, BM) where s=x+y, d=x-y:
// mux=(Bs+Bd)/2, muy=(Bs-Bd)/2; BP=blur(s^2), BM=blur(d^2).
// v_rcp_f32: den >= C1*C2 > 0; ~1e-6 rel err, far under tolerance.
__device__ __forceinline__ float ssim_px(float Bs, float Bd, float BP, float BM) {
    float mx = 0.5f*(Bs + Bd), my = 0.5f*(Bs - Bd);
    float A = mx*mx, B = my*my, mxy = mx*my;
    float sumsq = 0.5f*(BP + BM) - A - B;   // sigx2 + sigy2
    float sxy   = 0.25f*(BP - BM) - mxy;    // sigxy
    float num = (2.f*mxy + C1c) * (2.f*sxy + C2c);
    float den = (A + B + C1c) * (sumsq + C2c);
    return num * __builtin_amdgcn_rcpf(den);
}

// 512 threads, 1 col/thread in V, 4 cols/thread in H. 4-row barrier groups,
// single 34KB buffer. Raw s_barrier + lgkmcnt(0) only (prefetched global
// loads never drained at barriers). Finalization fused: fixed-point int64
// atomicAdd (deterministic, order-independent) + ticket; last block writes
// d_out. No second kernel launch.
__global__ __launch_bounds__(512, 3) void ssim_strip(
    const float* __restrict__ in, const float* __restrict__ tgt,
    const float* __restrict__ w, unsigned long long* __restrict__ ws,
    float* __restrict__ out)
{
    __shared__ float4 buf[4*ROWP];      // 2128 float4 = 34 KB
    __shared__ float g1s[16];
    __shared__ float red[8];

    const int tid   = threadIdx.x;
    const int strip = blockIdx.x;
    const int plane = blockIdx.y;
    const int r0 = strip * SROWS;
    const float* __restrict__ ip = in  + (size_t)plane * (IMG*IMG);
    const float* __restrict__ tp = tgt + (size_t)plane * (IMG*IMG);

    // 1D factor = row sums of 2D kernel (exact: w2d = outer(g,g), sum g = 1)
    if (tid < 11) {
        float s = 0.f;
        #pragma unroll
        for (int j = 0; j < 11; ++j) s += w[tid*11 + j];
        g1s[tid] = s;
    }
    __syncthreads();
    float g[11];
    #pragma unroll
    for (int j = 0; j < 11; ++j)
        g[j] = __int_as_float(__builtin_amdgcn_readfirstlane(__float_as_int(g1s[j])));

    v2f sd[16];                 // ring: input row k -> slot k & 15 (static)
    float acc = 0.f;
    const int wbase = (tid & 3) * RPITCH + (tid >> 2);   // V-write addr (f4)
    const int hr = tid >> 7;    // H: row in group (0..3), wave-uniform
    const int ht = tid & 127;   // H: col group -> cols 4ht..4ht+3
    const int hb = hr * ROWP + ht;

#define LD1(ROW, X, Y) \
    { const int r_ = r0 + (ROW); \
      X = (r_ < IMG) ? ip[r_*IMG + tid] : 0.f; \
      Y = (r_ < IMG) ? tp[r_*IMG + tid] : 0.f; }

#define INS(ROW, X, Y) sd[(ROW) & 15] = (v2f){(X) + (Y), (X) - (Y)};

    // V-blur rows 4T..4T+3 (input row 4T+j feeds out-row v for v<=j<=v+10,
    // weight g[j-v]); squares shared by all 4 rows.
#define VWR(T) \
    { v2f a0=(v2f)(0.f),p0=(v2f)(0.f),a1=(v2f)(0.f),p1=(v2f)(0.f); \
      v2f a2=(v2f)(0.f),p2=(v2f)(0.f),a3=(v2f)(0.f),p3=(v2f)(0.f); \
      _Pragma("unroll") \
      for (int j = 0; j < 14; ++j) { \
        v2f s = sd[(4*(T) + j) & 15]; \
        v2f q = s * s; \
        if (j <= 10)           { const float wj=g[j];   a0+=wj*s; p0+=wj*q; } \
        if (j >= 1 && j <= 11) { const float wj=g[j-1]; a1+=wj*s; p1+=wj*q; } \
        if (j >= 2 && j <= 12) { const float wj=g[j-2]; a2+=wj*s; p2+=wj*q; } \
        if (j >= 3)            { const float wj=g[j-3]; a3+=wj*s; p3+=wj*q; } \
      } \
      buf[0*ROWP + wbase] = make_float4(a0.x, a0.y, p0.x, p0.y); \
      buf[1*ROWP + wbase] = make_float4(a1.x, a1.y, p1.x, p1.y); \
      buf[2*ROWP + wbase] = make_float4(a2.x, a2.y, p2.x, p2.y); \
      buf[3*ROWP + wbase] = make_float4(a3.x, a3.y, p3.x, p3.y); }

    // H-pass: tap col 4ht+j lives at region j&3, idx ht+(j>>2).
#define HPASS(T) \
    { v2f s0=(v2f)(0.f),q0=(v2f)(0.f),s1=(v2f)(0.f),q1=(v2f)(0.f); \
      v2f s2=(v2f)(0.f),q2=(v2f)(0.f),s3=(v2f)(0.f),q3=(v2f)(0.f); \
      _Pragma("unroll") \
      for (int j = 0; j < 14; ++j) { \
        float4 v = buf[hb + (j&3)*RPITCH + (j>>2)]; \
        v2f vs = (v2f){v.x, v.y}, vp = (v2f){v.z, v.w}; \
        if (j <= 10)           { const float wj=g[j];   s0+=wj*vs; q0+=wj*vp; } \
        if (j >= 1 && j <= 11) { const float wj=g[j-1]; s1+=wj*vs; q1+=wj*vp; } \
        if (j >= 2 && j <= 12) { const float wj=g[j-2]; s2+=wj*vs; q2+=wj*vp; } \
        if (j >= 3)            { const float wj=g[j-3]; s3+=wj*vs; q3+=wj*vp; } \
      } \
      const int oy = r0 + 4*(T) + hr; \
      const int oc = 4*ht; \
      if (oy < OUT_N) { \
        if (oc     < OUT_N) acc += ssim_px(s0.x,s0.y,q0.x,q0.y); \
        if (oc + 1 < OUT_N) acc += ssim_px(s1.x,s1.y,q1.x,q1.y); \
        if (oc + 2 < OUT_N) acc += ssim_px(s2.x,s2.y,q2.x,q2.y); \
        if (oc + 3 < OUT_N) acc += ssim_px(s3.x,s3.y,q3.x,q3.y); \
      } }

#define BARRIER() \
    asm volatile("s_waitcnt lgkmcnt(0)" ::: "memory"); \
    __builtin_amdgcn_s_barrier(); \
    __builtin_amdgcn_sched_barrier(0);

#define GISSUE(T) \
    LD1(4*(T)+14, f0x, f0y) LD1(4*(T)+15, f1x, f1y) \
    LD1(4*(T)+16, f2x, f2y) LD1(4*(T)+17, f3x, f3y)
#define GINSERT(T) \
    INS(4*(T)+14, f0x, f0y) INS(4*(T)+15, f1x, f1y) \
    INS(4*(T)+16, f2x, f2y) INS(4*(T)+17, f3x, f3y)

    float f0x, f0y, f1x, f1y, f2x, f2y, f3x, f3y;

    // Prologue: rows 0..13 into ring, depth-2 staggered issue.
    float ax, ay, bx, by;
    LD1(0, ax, ay)   LD1(1, bx, by)
    INS(0, ax, ay)   LD1(2, ax, ay)
    INS(1, bx, by)   LD1(3, bx, by)
    INS(2, ax, ay)   LD1(4, ax, ay)
    INS(3, bx, by)   LD1(5, bx, by)
    INS(4, ax, ay)   LD1(6, ax, ay)
    INS(5, bx, by)   LD1(7, bx, by)
    INS(6, ax, ay)   LD1(8, ax, ay)
    INS(7, bx, by)   LD1(9, bx, by)
    INS(8, ax, ay)   LD1(10, ax, ay)
    INS(9, bx, by)   LD1(11, bx, by)
    INS(10, ax, ay)  LD1(12, ax, ay)
    INS(11, bx, by)  LD1(13, bx, by)
    INS(12, ax, ay)  INS(13, bx, by)

    // 4 groups x 4 rows = 16 output rows. Loads for group T+1's new rows are
    // issued before VWR(T) and consumed after HPASS(T) (~1 group of slack).
    GISSUE(0) VWR(0) BARRIER() HPASS(0) GINSERT(0) BARRIER()
    GISSUE(1) VWR(1) BARRIER() HPASS(1) GINSERT(1) BARRIER()
    GISSUE(2) VWR(2) BARRIER() HPASS(2) GINSERT(2) BARRIER()
              VWR(3) BARRIER() HPASS(3)

    // block reduction: wave shuffle, then 8 wave-partials through LDS
    #pragma unroll
    for (int off = 32; off > 0; off >>= 1)
        acc += __shfl_down(acc, off, 64);
    const int lane = tid & 63, wv = tid >> 6;
    if (lane == 0) red[wv] = acc;
    __syncthreads();
    if (tid == 0) {
        float t = 0.f;
        #pragma unroll
        for (int i = 0; i < 8; ++i) t += red[i];
        // Deterministic single-pass finalization: fixed-point (2^24) int64
        // atomicAdd is order-independent; ticket elects the last block.
        long long q = (long long)rintf(t * FPSCALE);
        atomicAdd(ws, (unsigned long long)q);           // device-scope
        __threadfence();
        unsigned int old = atomicAdd((unsigned int*)(ws + 1), 1u);
        if (old == NBLOCKS - 1) {
            __threadfence();
            unsigned long long a = atomicAdd(ws, 0ull); // coherent read
            double s = (double)(long long)a / (double)FPSCALE;
            out[0] = (float)(1.0 - s / (double)NPLANE);
        }
    }
}

extern "C" void kernel_launch(void* const* d_in, const int* in_sizes, int n_in,
                              void* d_out, int out_size, void* d_ws, size_t ws_size,
                              hipStream_t stream) {
    const float* in  = (const float*)d_in[0];
    const float* tgt = (const float*)d_in[1];
    const float* wt  = (const float*)d_in[2];
    float* out = (float*)d_out;

    // ws[0] = int64 fixed-point accumulator, ws[1] = ticket. Zeroed every
    // call (poison-proof, replay-deterministic). Async memset is capture-safe.
    hipMemsetAsync(d_ws, 0, 16, stream);
    dim3 grid(NSTRIP, NPLANE);   // 32 strips x 48 planes = 1536 blocks
    ssim_strip<<<grid, 512, 0, stream>>>(in, tgt, wt,
                                         (unsigned long long*)d_ws, out);
}

// Round 16
// 51.310 us; speedup vs baseline: 1.5774x; 1.5774x over previous
//
#include <hip/hip_runtime.h>

typedef float v2f __attribute__((ext_vector_type(2)));

#define IMG 512
#define OUT_N 502
#define NPLANE 48
#define NSTRIP 32            // 16 output rows per strip
#define SROWS 16
#define RPITCH 133           // region pitch (float4 units) in row buffer
#define ROWP (4*RPITCH)      // 532 float4 per buffered V-row
#define C1c 0.0001f
#define C2c 0.0004f

// ssim from H-blurred (Bs, Bd, BP, BM) where s=x+y, d=x-y:
// mux=(Bs+Bd)/2, muy=(Bs-Bd)/2; BP=blur(s^2), BM=blur(d^2).
// v_rcp_f32 for the final divide: den >= C1*C2 > 0; ~1e-6 rel err vs 1.125 tol.
__device__ __forceinline__ float ssim_px(float Bs, float Bd, float BP, float BM) {
    float mx = 0.5f*(Bs + Bd), my = 0.5f*(Bs - Bd);
    float A = mx*mx, B = my*my, mxy = mx*my;
    float sumsq = 0.5f*(BP + BM) - A - B;   // sigx2 + sigy2
    float sxy   = 0.25f*(BP - BM) - mxy;    // sigxy
    float num = (2.f*mxy + C1c) * (2.f*sxy + C2c);
    float den = (A + B + C1c) * (sumsq + C2c);
    return num * __builtin_amdgcn_rcpf(den);
}

// 512 threads, 1 col/thread in V, 4 cols/thread in H. 4-row barrier groups:
// V-blur 4 rows from a 16-entry (s,d) float2 ring (32 VGPR, &15 static slots),
// write one 4-row LDS buffer (mod-4 column regions, pitch 133: H reads are
// idx-stride-1 conflict-free, V writes uniform over bank-quads), barrier,
// H-pass 4 rows x 128 thr x 4 cols (14 b128 per 4 px = 3.5/px),
// barrier. Raw s_barrier + lgkmcnt only -- prefetched global loads (depth ~1
// group ahead) never drained at barriers.
__global__ __launch_bounds__(512, 3) void ssim_strip(
    const float* __restrict__ in, const float* __restrict__ tgt,
    const float* __restrict__ w, float* __restrict__ partial)
{
    __shared__ float4 buf[4*ROWP];      // 2128 float4 = 34 KB
    __shared__ float g1s[16];
    __shared__ float red[8];

    const int tid   = threadIdx.x;
    const int strip = blockIdx.x;
    const int plane = blockIdx.y;
    const int r0 = strip * SROWS;
    const float* __restrict__ ip = in  + (size_t)plane * (IMG*IMG);
    const float* __restrict__ tp = tgt + (size_t)plane * (IMG*IMG);

    // 1D factor = row sums of 2D kernel (exact: w2d = outer(g,g), sum g = 1)
    if (tid < 11) {
        float s = 0.f;
        #pragma unroll
        for (int j = 0; j < 11; ++j) s += w[tid*11 + j];
        g1s[tid] = s;
    }
    __syncthreads();
    float g[11];
    #pragma unroll
    for (int j = 0; j < 11; ++j)
        g[j] = __int_as_float(__builtin_amdgcn_readfirstlane(__float_as_int(g1s[j])));

    v2f sd[16];                 // ring: input row k -> slot k & 15 (static)
    float acc = 0.f;
    const int wbase = (tid & 3) * RPITCH + (tid >> 2);   // V-write addr (f4)
    const int hr = tid >> 7;    // H: row in group (0..3), wave-uniform
    const int ht = tid & 127;   // H: col group -> cols 4ht..4ht+3
    const int hb = hr * ROWP + ht;

#define LD1(ROW, X, Y) \
    { const int r_ = r0 + (ROW); \
      X = (r_ < IMG) ? ip[r_*IMG + tid] : 0.f; \
      Y = (r_ < IMG) ? tp[r_*IMG + tid] : 0.f; }

#define INS(ROW, X, Y) sd[(ROW) & 15] = (v2f){(X) + (Y), (X) - (Y)};

    // V-blur rows 4T..4T+3 (taps j: input row 4T+j feeds out-row v for
    // v<=j<=v+10, weight g[j-v]); squares shared by all 4 rows.
#define VWR(T) \
    { v2f a0=(v2f)(0.f),p0=(v2f)(0.f),a1=(v2f)(0.f),p1=(v2f)(0.f); \
      v2f a2=(v2f)(0.f),p2=(v2f)(0.f),a3=(v2f)(0.f),p3=(v2f)(0.f); \
      _Pragma("unroll") \
      for (int j = 0; j < 14; ++j) { \
        v2f s = sd[(4*(T) + j) & 15]; \
        v2f q = s * s; \
        if (j <= 10)           { const float wj=g[j];   a0+=wj*s; p0+=wj*q; } \
        if (j >= 1 && j <= 11) { const float wj=g[j-1]; a1+=wj*s; p1+=wj*q; } \
        if (j >= 2 && j <= 12) { const float wj=g[j-2]; a2+=wj*s; p2+=wj*q; } \
        if (j >= 3)            { const float wj=g[j-3]; a3+=wj*s; p3+=wj*q; } \
      } \
      buf[0*ROWP + wbase] = make_float4(a0.x, a0.y, p0.x, p0.y); \
      buf[1*ROWP + wbase] = make_float4(a1.x, a1.y, p1.x, p1.y); \
      buf[2*ROWP + wbase] = make_float4(a2.x, a2.y, p2.x, p2.y); \
      buf[3*ROWP + wbase] = make_float4(a3.x, a3.y, p3.x, p3.y); }

    // H-pass: tap col 4ht+j lives at region j&3, idx ht+(j>>2).
#define HPASS(T) \
    { v2f s0=(v2f)(0.f),q0=(v2f)(0.f),s1=(v2f)(0.f),q1=(v2f)(0.f); \
      v2f s2=(v2f)(0.f),q2=(v2f)(0.f),s3=(v2f)(0.f),q3=(v2f)(0.f); \
      _Pragma("unroll") \
      for (int j = 0; j < 14; ++j) { \
        float4 v = buf[hb + (j&3)*RPITCH + (j>>2)]; \
        v2f vs = (v2f){v.x, v.y}, vp = (v2f){v.z, v.w}; \
        if (j <= 10)           { const float wj=g[j];   s0+=wj*vs; q0+=wj*vp; } \
        if (j >= 1 && j <= 11) { const float wj=g[j-1]; s1+=wj*vs; q1+=wj*vp; } \
        if (j >= 2 && j <= 12) { const float wj=g[j-2]; s2+=wj*vs; q2+=wj*vp; } \
        if (j >= 3)            { const float wj=g[j-3]; s3+=wj*vs; q3+=wj*vp; } \
      } \
      const int oy = r0 + 4*(T) + hr; \
      const int oc = 4*ht; \
      if (oy < OUT_N) { \
        if (oc     < OUT_N) acc += ssim_px(s0.x,s0.y,q0.x,q0.y); \
        if (oc + 1 < OUT_N) acc += ssim_px(s1.x,s1.y,q1.x,q1.y); \
        if (oc + 2 < OUT_N) acc += ssim_px(s2.x,s2.y,q2.x,q2.y); \
        if (oc + 3 < OUT_N) acc += ssim_px(s3.x,s3.y,q3.x,q3.y); \
      } }

#define BARRIER() \
    asm volatile("s_waitcnt lgkmcnt(0)" ::: "memory"); \
    __builtin_amdgcn_s_barrier(); \
    __builtin_amdgcn_sched_barrier(0);

#define GISSUE(T) \
    LD1(4*(T)+14, f0x, f0y) LD1(4*(T)+15, f1x, f1y) \
    LD1(4*(T)+16, f2x, f2y) LD1(4*(T)+17, f3x, f3y)
#define GINSERT(T) \
    INS(4*(T)+14, f0x, f0y) INS(4*(T)+15, f1x, f1y) \
    INS(4*(T)+16, f2x, f2y) INS(4*(T)+17, f3x, f3y)

    float f0x, f0y, f1x, f1y, f2x, f2y, f3x, f3y;

    // Prologue: rows 0..13 into ring, depth-2 staggered issue.
    float ax, ay, bx, by;
    LD1(0, ax, ay)   LD1(1, bx, by)
    INS(0, ax, ay)   LD1(2, ax, ay)
    INS(1, bx, by)   LD1(3, bx, by)
    INS(2, ax, ay)   LD1(4, ax, ay)
    INS(3, bx, by)   LD1(5, bx, by)
    INS(4, ax, ay)   LD1(6, ax, ay)
    INS(5, bx, by)   LD1(7, bx, by)
    INS(6, ax, ay)   LD1(8, ax, ay)
    INS(7, bx, by)   LD1(9, bx, by)
    INS(8, ax, ay)   LD1(10, ax, ay)
    INS(9, bx, by)   LD1(11, bx, by)
    INS(10, ax, ay)  LD1(12, ax, ay)
    INS(11, bx, by)  LD1(13, bx, by)
    INS(12, ax, ay)  INS(13, bx, by)

    // 4 groups x 4 rows = 16 output rows. Loads for group T+1's new rows are
    // issued before VWR(T) and consumed after HPASS(T) (~1 group of slack).
    GISSUE(0) VWR(0) BARRIER() HPASS(0) GINSERT(0) BARRIER()
    GISSUE(1) VWR(1) BARRIER() HPASS(1) GINSERT(1) BARRIER()
    GISSUE(2) VWR(2) BARRIER() HPASS(2) GINSERT(2) BARRIER()
              VWR(3) BARRIER() HPASS(3)

    // block reduction: wave shuffle, then 8 wave-partials through LDS
    #pragma unroll
    for (int off = 32; off > 0; off >>= 1)
        acc += __shfl_down(acc, off, 64);
    const int lane = tid & 63, wv = tid >> 6;
    if (lane == 0) red[wv] = acc;
    __syncthreads();
    if (tid == 0) {
        float t = 0.f;
        #pragma unroll
        for (int i = 0; i < 8; ++i) t += red[i];
        partial[plane * NSTRIP + strip] = t;
    }
}

// Deterministic final reduction: fixed traversal, double accumulation.
__global__ __launch_bounds__(256) void ssim_final(
    const float* __restrict__ partial, int n, float* __restrict__ out)
{
    __shared__ double red[256];
    double s = 0.0;
    for (int i = threadIdx.x; i < n; i += 256) s += (double)partial[i];
    red[threadIdx.x] = s;
    __syncthreads();
    for (int off = 128; off > 0; off >>= 1) {
        if (threadIdx.x < off) red[threadIdx.x] += red[threadIdx.x + off];
        __syncthreads();
    }
    if (threadIdx.x == 0) out[0] = (float)(1.0 - red[0] / (double)NPLANE);
}

extern "C" void kernel_launch(void* const* d_in, const int* in_sizes, int n_in,
                              void* d_out, int out_size, void* d_ws, size_t ws_size,
                              hipStream_t stream) {
    const float* in  = (const float*)d_in[0];
    const float* tgt = (const float*)d_in[1];
    const float* wt  = (const float*)d_in[2];
    float* out  = (float*)d_out;
    float* part = (float*)d_ws;

    dim3 grid(NSTRIP, NPLANE);   // 32 strips x 48 planes = 1536 blocks
    ssim_strip<<<grid, 512, 0, stream>>>(in, tgt, wt, part);
    ssim_final<<<1, 256, 0, stream>>>(part, NSTRIP * NPLANE, out);
}

// Round 17
// 47.368 us; speedup vs baseline: 1.7086x; 1.0832x over previous
//
#include <hip/hip_runtime.h>

typedef __attribute__((ext_vector_type(8))) _Float16 f16x8;
typedef __attribute__((ext_vector_type(4))) float f32x4;

#define IMG 512
#define OUT_N 502
#define NPLANE 48
#define NBAND 32             // 16 output rows per band
#define VP 520               // LDS pitch (fp16): 512 + 8 pad
#define C1c 0.0001f
#define C2c 0.0004f

// P = blur(s^2), M = blur(d^2) with s=x+y, d=x-y; mx=blur(x), my=blur(y).
__device__ __forceinline__ float ssim_px(float mx, float my, float P, float M) {
    float A = mx*mx, B = my*my, mxy = mx*my;
    float sumsq = 0.5f*(P+M) - A - B;   // sigx2 + sigy2
    float sxy   = 0.25f*(P-M) - mxy;    // sigxy
    float num = (2.f*mxy + C1c) * (2.f*sxy + C2c);
    float den = (A + B + C1c) * (sumsq + C2c);
    return num * __builtin_amdgcn_rcpf(den);
}

// Block = one 16-row output band of one plane, 512 threads (8 waves).
// Both blur passes are banded matmuls on the (idle) matrix pipe:
//   V: D = Band(16x32) x Data(32x16); H: D = Data(16x32) x Band(32x16)
// Band[i][k] = g[k-i] (zero outside 0..10). Lane formula g[kB+q-(lane&15)]
// is identical for the A-side (row=lane&15) and B-side (col=lane&15) layouts
// -> ONE fragment serves both. fp16 fragments (5e-4 rel err; fp32 accum).
// Weight-zero k>=26 makes edge clamping provably safe (garbage x 0).
// V writes fp16 LDS (4 fields x 16 x 520 = 66.5 KB, 2 blocks/CU); single
// barrier; H A-frags are one aligned ds_read_b128 per field.
__global__ __launch_bounds__(512, 2) void ssim_band(
    const float* __restrict__ in, const float* __restrict__ tgt,
    const float* __restrict__ w, float* __restrict__ partial)
{
    __shared__ __attribute__((aligned(16))) _Float16 vlds[4][16][VP];
    __shared__ float g1s[16];
    __shared__ float red[8];

    const int tid   = threadIdx.x;
    const int lane  = tid & 63;
    const int wv    = tid >> 6;          // wave id 0..7
    const int band  = blockIdx.x;
    const int plane = blockIdx.y;
    const int r0 = band * 16;
    const float* __restrict__ ip = in  + (size_t)plane * (IMG*IMG);
    const float* __restrict__ tp = tgt + (size_t)plane * (IMG*IMG);

    // 1D factor = row sums of 2D kernel (exact: w2d = outer(g,g), sum g = 1)
    if (tid < 11) {
        float s = 0.f;
        #pragma unroll
        for (int j = 0; j < 11; ++j) s += w[tid*11 + j];
        g1s[tid] = s;
    }
    __syncthreads();
    float g[11];
    #pragma unroll
    for (int j = 0; j < 11; ++j)
        g[j] = __int_as_float(__builtin_amdgcn_readfirstlane(__float_as_int(g1s[j])));

    const int fi = lane & 15;            // A-row / B-col / D-col index
    const int kg = lane >> 4;            // k-group (0..3)
    const int kB = kg * 8;               // k base for this lane

    // Banded weight fragment (static-indexed build; no dynamic g[] index).
    f16x8 band_f;
    #pragma unroll
    for (int q = 0; q < 8; ++q) {
        float wq = 0.f;
        #pragma unroll
        for (int j = 0; j <= 10; ++j)
            wq = (kB + q - fi == j) ? g[j] : wq;
        band_f[q] = (_Float16)wq;
    }

    float acc = 0.f;
    const f32x4 z = {0.f, 0.f, 0.f, 0.f};

    // ---- V phase: wave wv covers col-tiles 4wv..4wv+3 (16 cols each) ----
    // B-frag (data): lane holds in[r0 + kB + q][c0 + fi]. k>=26 has zero
    // weight for every output row -> skip those loads; row clamp only
    // matters at band 31 where affected weights are also zero.
#define VLOAD(T, XS, YS) \
    { const int c_ = (wv*4 + (T))*16 + fi; \
      const int rb_ = r0 + kB; \
      _Pragma("unroll") \
      for (int q = 0; q < 8; ++q) { \
          if (kB + q <= 25) { \
              const int rr = min(rb_ + q, IMG - 1); \
              XS[q] = ip[rr*IMG + c_]; YS[q] = tp[rr*IMG + c_]; \
          } else { XS[q] = 0.f; YS[q] = 0.f; } \
      } }

#define VPROC(T, XS, YS) \
    { f16x8 fX, fY, fP, fM; \
      _Pragma("unroll") \
      for (int q = 0; q < 8; ++q) { \
          const float x = XS[q], y = YS[q]; \
          const float s = x + y, d = x - y; \
          fX[q] = (_Float16)x;     fY[q] = (_Float16)y; \
          fP[q] = (_Float16)(s*s); fM[q] = (_Float16)(d*d); \
      } \
      f32x4 dX = __builtin_amdgcn_mfma_f32_16x16x32_f16(band_f, fX, z, 0, 0, 0); \
      f32x4 dY = __builtin_amdgcn_mfma_f32_16x16x32_f16(band_f, fY, z, 0, 0, 0); \
      f32x4 dP = __builtin_amdgcn_mfma_f32_16x16x32_f16(band_f, fP, z, 0, 0, 0); \
      f32x4 dM = __builtin_amdgcn_mfma_f32_16x16x32_f16(band_f, fM, z, 0, 0, 0); \
      const int c_ = (wv*4 + (T))*16 + fi; \
      _Pragma("unroll") \
      for (int m = 0; m < 4; ++m) { \
          const int orow = kg*4 + m;        /* D: col=lane&15, row=kg*4+m */ \
          vlds[0][orow][c_] = (_Float16)dX[m]; \
          vlds[1][orow][c_] = (_Float16)dY[m]; \
          vlds[2][orow][c_] = (_Float16)dP[m]; \
          vlds[3][orow][c_] = (_Float16)dM[m]; \
      } }

    float xA[8], yA[8], xB[8], yB[8];
    VLOAD(0, xA, yA)
    VLOAD(1, xB, yB)     // depth-2 prefetch
    VPROC(0, xA, yA)
    VLOAD(2, xA, yA)
    VPROC(1, xB, yB)
    VLOAD(3, xB, yB)
    VPROC(2, xA, yA)
    VPROC(3, xB, yB)

    __syncthreads();     // the only inter-phase barrier

    // ---- H phase: A-frag = v[fi][c0 + kB + q] (one b128/field), B = band ----
    // Col clamp to 504 only bites at c0=496 for k-groups whose weights are
    // zero on all valid out cols (oc<502 masks the rest).
#define HPROC(T) \
    { const int c0_ = (wv*4 + (T))*16; \
      const int kb_ = min(c0_ + kB, IMG - 8); \
      f16x8 aX = *reinterpret_cast<const f16x8*>(&vlds[0][fi][kb_]); \
      f16x8 aY = *reinterpret_cast<const f16x8*>(&vlds[1][fi][kb_]); \
      f16x8 aP = *reinterpret_cast<const f16x8*>(&vlds[2][fi][kb_]); \
      f16x8 aM = *reinterpret_cast<const f16x8*>(&vlds[3][fi][kb_]); \
      f32x4 dX = __builtin_amdgcn_mfma_f32_16x16x32_f16(aX, band_f, z, 0, 0, 0); \
      f32x4 dY = __builtin_amdgcn_mfma_f32_16x16x32_f16(aY, band_f, z, 0, 0, 0); \
      f32x4 dP = __builtin_amdgcn_mfma_f32_16x16x32_f16(aP, band_f, z, 0, 0, 0); \
      f32x4 dM = __builtin_amdgcn_mfma_f32_16x16x32_f16(aM, band_f, z, 0, 0, 0); \
      const int oc = c0_ + fi; \
      if (oc < OUT_N) { \
          _Pragma("unroll") \
          for (int m = 0; m < 4; ++m) { \
              const int oy = r0 + kg*4 + m; \
              if (oy < OUT_N) \
                  acc += ssim_px(dX[m], dY[m], dP[m], dM[m]); \
          } } }

    HPROC(0) HPROC(1) HPROC(2) HPROC(3)

    // block reduction: wave shuffle, then 8 wave-partials through LDS
    #pragma unroll
    for (int off = 32; off > 0; off >>= 1)
        acc += __shfl_down(acc, off, 64);
    if ((lane & 63) == 0) red[wv] = acc;
    __syncthreads();
    if (tid == 0) {
        float t = 0.f;
        #pragma unroll
        for (int i = 0; i < 8; ++i) t += red[i];
        partial[plane * NBAND + band] = t;
    }
}

// Deterministic final reduction: fixed traversal, double accumulation.
__global__ __launch_bounds__(256) void ssim_final(
    const float* __restrict__ partial, int n, float* __restrict__ out)
{
    __shared__ double red[256];
    double s = 0.0;
    for (int i = threadIdx.x; i < n; i += 256) s += (double)partial[i];
    red[threadIdx.x] = s;
    __syncthreads();
    for (int off = 128; off > 0; off >>= 1) {
        if (threadIdx.x < off) red[threadIdx.x] += red[threadIdx.x + off];
        __syncthreads();
    }
    if (threadIdx.x == 0) out[0] = (float)(1.0 - red[0] / (double)NPLANE);
}

extern "C" void kernel_launch(void* const* d_in, const int* in_sizes, int n_in,
                              void* d_out, int out_size, void* d_ws, size_t ws_size,
                              hipStream_t stream) {
    const float* in  = (const float*)d_in[0];
    const float* tgt = (const float*)d_in[1];
    const float* wt  = (const float*)d_in[2];
    float* out  = (float*)d_out;
    float* part = (float*)d_ws;

    dim3 grid(NBAND, NPLANE);    // 32 bands x 48 planes = 1536 blocks
    ssim_band<<<grid, 512, 0, stream>>>(in, tgt, wt, part);
    ssim_final<<<1, 256, 0, stream>>>(part, NBAND * NPLANE, out);
}

// Round 19
// 40.617 us; speedup vs baseline: 1.9926x; 1.1662x over previous
//
#include <hip/hip_runtime.h>

typedef __attribute__((ext_vector_type(8))) _Float16 f16x8;
typedef __attribute__((ext_vector_type(4))) float f32x4;
typedef __attribute__((ext_vector_type(4))) _Float16 h4;

#define IMG 512
#define OUT_N 502
#define NPLANE 48
#define NBAND 32             // 16 output rows per band
#define VP 520               // LDS pitch (fp16): 512 + 8 pad (keeps b128 align)
#define C1c 0.0001f
#define C2c 0.0004f

// P = blur(s^2), M = blur(d^2) with s=x+y, d=x-y; mx=blur(x), my=blur(y).
__device__ __forceinline__ float ssim_px(float mx, float my, float P, float M) {
    float A = mx*mx, B = my*my, mxy = mx*my;
    float sumsq = 0.5f*(P+M) - A - B;   // sigx2 + sigy2
    float sxy   = 0.25f*(P-M) - mxy;    // sigxy
    float num = (2.f*mxy + C1c) * (2.f*sxy + C2c);
    float den = (A + B + C1c) * (sumsq + C2c);
    return num * __builtin_amdgcn_rcpf(den);
}

// Block = one 16-row output band, 512 threads (8 waves). Both blurs are banded
// matmuls on the matrix pipe. V is computed TRANSPOSED vs R17:
//   V: D = Data(16x32) x Band(32x16)  -> lane holds out-row fi, 4 consecutive
//      cols kg*4+m  -> one packed ds_write_b64 per field (was 16 ds_write_b16).
// Band[k][j] = g[k-j]; lane formula g[kB+q-fi] serves A- and B-side alike.
// k>=26 has zero weight for every out row/col -> row-clamped loads need no
// zero-fill (finite garbage x 0 = 0). H: D = Vdata(16x32) x Band(32x16),
// A-frag = one aligned ds_read_b128 per field. fp16 fragments, fp32 accum.
__global__ __launch_bounds__(512, 2) void ssim_band(
    const float* __restrict__ in, const float* __restrict__ tgt,
    const float* __restrict__ w, float* __restrict__ partial)
{
    __shared__ __attribute__((aligned(16))) _Float16 vlds[4][16][VP];
    __shared__ float g1s[16];
    __shared__ float red[8];

    const int tid   = threadIdx.x;
    const int lane  = tid & 63;
    const int wv    = tid >> 6;          // wave id 0..7
    const int band  = blockIdx.x;
    const int plane = blockIdx.y;
    const int r0 = band * 16;
    const float* __restrict__ ip = in  + (size_t)plane * (IMG*IMG);
    const float* __restrict__ tp = tgt + (size_t)plane * (IMG*IMG);

    // 1D factor = row sums of the 2D kernel (exact: w2d = outer(g,g), sum = 1)
    if (tid < 11) {
        float s = 0.f;
        #pragma unroll
        for (int j = 0; j < 11; ++j) s += w[tid*11 + j];
        g1s[tid] = s;
    }
    __syncthreads();
    float g[11];
    #pragma unroll
    for (int j = 0; j < 11; ++j)
        g[j] = __int_as_float(__builtin_amdgcn_readfirstlane(__float_as_int(g1s[j])));

    const int fi = lane & 15;            // A-row / B-col / D-col index
    const int kg = lane >> 4;            // k-group (0..3)
    const int kB = kg * 8;               // k base for this lane

    // Banded weight fragment: band_f[q] = g[kB+q - fi] (zero outside 0..10).
    f16x8 band_f;
    #pragma unroll
    for (int q = 0; q < 8; ++q) {
        float wq = 0.f;
        #pragma unroll
        for (int j = 0; j <= 10; ++j)
            wq = (kB + q - fi == j) ? g[j] : wq;
        band_f[q] = (_Float16)wq;
    }

    float acc = 0.f;
    const f32x4 z = {0.f, 0.f, 0.f, 0.f};

    // Hoisted V-load indices: row r0+kB+q (clamped), col base wv*64 + fi.
    // Tile T adds 16*T (a 64-byte immediate in the load encoding).
    int idx[8];
    #pragma unroll
    for (int q = 0; q < 8; ++q) {
        const int rr = min(r0 + kB + q, IMG - 1);
        idx[q] = rr * IMG + wv * 64 + fi;
    }

#define VLOAD(T, XS, YS) \
    { _Pragma("unroll") \
      for (int q = 0; q < 8; ++q) { \
          XS[q] = ip[idx[q] + 16*(T)]; \
          YS[q] = tp[idx[q] + 16*(T)]; \
      } }

#define VSTORE(F, D) \
    { h4 wr_ = {(_Float16)(D)[0], (_Float16)(D)[1], \
                (_Float16)(D)[2], (_Float16)(D)[3]}; \
      *reinterpret_cast<h4*>(&vlds[F][fi][cb_]) = wr_; }

#define VPROC(T, XS, YS) \
    { f16x8 fX, fY, fP, fM; \
      _Pragma("unroll") \
      for (int q = 0; q < 8; ++q) { \
          const float x = XS[q], y = YS[q]; \
          const float s = x + y, d = x - y; \
          fX[q] = (_Float16)x;     fY[q] = (_Float16)y; \
          fP[q] = (_Float16)(s*s); fM[q] = (_Float16)(d*d); \
      } \
      f32x4 dX = __builtin_amdgcn_mfma_f32_16x16x32_f16(fX, band_f, z, 0, 0, 0); \
      f32x4 dY = __builtin_amdgcn_mfma_f32_16x16x32_f16(fY, band_f, z, 0, 0, 0); \
      f32x4 dP = __builtin_amdgcn_mfma_f32_16x16x32_f16(fP, band_f, z, 0, 0, 0); \
      f32x4 dM = __builtin_amdgcn_mfma_f32_16x16x32_f16(fM, band_f, z, 0, 0, 0); \
      const int cb_ = (wv*4 + (T))*16 + kg*4; \
      VSTORE(0, dX) VSTORE(1, dY) VSTORE(2, dP) VSTORE(3, dM) }

    float xA[8], yA[8], xB[8], yB[8];
    VLOAD(0, xA, yA)
    VLOAD(1, xB, yB)     // depth-2 prefetch
    VPROC(0, xA, yA)
    VLOAD(2, xA, yA)
    VPROC(1, xB, yB)
    VLOAD(3, xB, yB)
    VPROC(2, xA, yA)
    VPROC(3, xB, yB)

    __syncthreads();     // the only inter-phase barrier

    // ---- H phase: A-frag = vlds[f][fi][c0+kB..+7] (one b128/field) ----
    // Col clamp to 504 only bites where the affected weights are zero.
#define HPROC(T) \
    { const int c0_ = (wv*4 + (T))*16; \
      const int kb_ = min(c0_ + kB, IMG - 8); \
      f16x8 aX = *reinterpret_cast<const f16x8*>(&vlds[0][fi][kb_]); \
      f16x8 aY = *reinterpret_cast<const f16x8*>(&vlds[1][fi][kb_]); \
      f16x8 aP = *reinterpret_cast<const f16x8*>(&vlds[2][fi][kb_]); \
      f16x8 aM = *reinterpret_cast<const f16x8*>(&vlds[3][fi][kb_]); \
      f32x4 dX = __builtin_amdgcn_mfma_f32_16x16x32_f16(aX, band_f, z, 0, 0, 0); \
      f32x4 dY = __builtin_amdgcn_mfma_f32_16x16x32_f16(aY, band_f, z, 0, 0, 0); \
      f32x4 dP = __builtin_amdgcn_mfma_f32_16x16x32_f16(aP, band_f, z, 0, 0, 0); \
      f32x4 dM = __builtin_amdgcn_mfma_f32_16x16x32_f16(aM, band_f, z, 0, 0, 0); \
      const int oc = c0_ + fi; \
      if (oc < OUT_N) { \
          _Pragma("unroll") \
          for (int m = 0; m < 4; ++m) { \
              const int oy = r0 + kg*4 + m; \
              if (oy < OUT_N) \
                  acc += ssim_px(dX[m], dY[m], dP[m], dM[m]); \
          } } }

    HPROC(0) HPROC(1) HPROC(2) HPROC(3)

    // block reduction: wave shuffle, then 8 wave-partials through LDS
    #pragma unroll
    for (int off = 32; off > 0; off >>= 1)
        acc += __shfl_down(acc, off, 64);
    if (lane == 0) red[wv] = acc;
    __syncthreads();
    if (tid == 0) {
        float t = 0.f;
        #pragma unroll
        for (int i = 0; i < 8; ++i) t += red[i];
        partial[plane * NBAND + band] = t;
    }
}

// Deterministic final reduction: fixed traversal, double accumulation.
__global__ __launch_bounds__(256) void ssim_final(
    const float* __restrict__ partial, int n, float* __restrict__ out)
{
    __shared__ double red[256];
    double s = 0.0;
    for (int i = threadIdx.x; i < n; i += 256) s += (double)partial[i];
    red[threadIdx.x] = s;
    __syncthreads();
    for (int off = 128; off > 0; off >>= 1) {
        if (threadIdx.x < off) red[threadIdx.x] += red[threadIdx.x + off];
        __syncthreads();
    }
    if (threadIdx.x == 0) out[0] = (float)(1.0 - red[0] / (double)NPLANE);
}

extern "C" void kernel_launch(void* const* d_in, const int* in_sizes, int n_in,
                              void* d_out, int out_size, void* d_ws, size_t ws_size,
                              hipStream_t stream) {
    const float* in  = (const float*)d_in[0];
    const float* tgt = (const float*)d_in[1];
    const float* wt  = (const float*)d_in[2];
    float* out  = (float*)d_out;
    float* part = (float*)d_ws;

    dim3 grid(NBAND, NPLANE);    // 32 bands x 48 planes = 1536 blocks
    ssim_band<<<grid, 512, 0, stream>>>(in, tgt, wt, part);
    ssim_final<<<1, 256, 0, stream>>>(part, NBAND * NPLANE, out);
}

// Round 20
// 39.386 us; speedup vs baseline: 2.0549x; 1.0312x over previous
//
#include <hip/hip_runtime.h>

typedef __attribute__((ext_vector_type(8))) _Float16 f16x8;
typedef __attribute__((ext_vector_type(4))) float f32x4;
typedef __attribute__((ext_vector_type(4))) _Float16 h4;
typedef __attribute__((ext_vector_type(2))) __fp16 hw2;
typedef __attribute__((ext_vector_type(2))) float v2f;

#define IMG 512
#define OUT_N 502
#define NPLANE 48
#define NBAND 32             // 16 output rows per band
#define VP 520               // LDS pitch (fp16): 512 + 8 pad (keeps b128 align)
#define C1c 0.0001f
#define C2c 0.0004f

union H8u { hw2 p[4]; f16x8 v; };
union H4u { hw2 p[2]; h4 v; };

// scalar ssim (edge band only)
__device__ __forceinline__ float ssim_px(float mx, float my, float P, float M) {
    float A = mx*mx, B = my*my, mxy = mx*my;
    float sumsq = 0.5f*(P+M) - A - B;
    float sxy   = 0.25f*(P-M) - mxy;
    float num = (2.f*mxy + C1c) * (2.f*sxy + C2c);
    float den = (A + B + C1c) * (sumsq + C2c);
    return num * __builtin_amdgcn_rcpf(den);
}

// packed-pair ssim: v_pk_*_f32 for the elementwise chain, scalar rcp x2
__device__ __forceinline__ float ssim_px2(v2f mx, v2f my, v2f P, v2f M) {
    v2f A = mx*mx, B = my*my, mxy = mx*my;
    v2f sumsq = 0.5f*(P+M) - A - B;
    v2f sxy   = 0.25f*(P-M) - mxy;
    v2f num = (2.f*mxy + C1c) * (2.f*sxy + C2c);
    v2f den = (A + B + C1c) * (sumsq + C2c);
    return num.x * __builtin_amdgcn_rcpf(den.x)
         + num.y * __builtin_amdgcn_rcpf(den.y);
}

// Block = one 16-row output band, 512 threads (8 waves). Both blurs are banded
// matmuls on the matrix pipe (R19 structure, layouts verified absmax 0.0):
//   V: D = Data(16x32) x Band(32x16) -> lane holds out-row fi, 4 consecutive
//      cols -> one packed ds_write_b64 per field.
//   H: D = Vdata(16x32) x Band(32x16), A-frag = one ds_read_b128 per field.
// R20 delta: VPROC/VSTORE/epilogue in packed math (v_cvt_pkrtz + v_pk_f16 +
// v_pk_f32), edge-row predicate hoisted to block-uniform branch.
__global__ __launch_bounds__(512, 2) void ssim_band(
    const float* __restrict__ in, const float* __restrict__ tgt,
    const float* __restrict__ w, float* __restrict__ partial)
{
    __shared__ __attribute__((aligned(16))) _Float16 vlds[4][16][VP];
    __shared__ float g1s[16];
    __shared__ float red[8];

    const int tid   = threadIdx.x;
    const int lane  = tid & 63;
    const int wv    = tid >> 6;          // wave id 0..7
    const int band  = blockIdx.x;
    const int plane = blockIdx.y;
    const int r0 = band * 16;
    const bool edge = (r0 + 16 > OUT_N);          // block-uniform (band 31)
    const float* __restrict__ ip = in  + (size_t)plane * (IMG*IMG);
    const float* __restrict__ tp = tgt + (size_t)plane * (IMG*IMG);

    // 1D factor = row sums of the 2D kernel (exact: w2d = outer(g,g), sum = 1)
    if (tid < 11) {
        float s = 0.f;
        #pragma unroll
        for (int j = 0; j < 11; ++j) s += w[tid*11 + j];
        g1s[tid] = s;
    }
    __syncthreads();
    float g[11];
    #pragma unroll
    for (int j = 0; j < 11; ++j)
        g[j] = __int_as_float(__builtin_amdgcn_readfirstlane(__float_as_int(g1s[j])));

    const int fi = lane & 15;            // A-row / B-col / D-col index
    const int kg = lane >> 4;            // k-group (0..3)
    const int kB = kg * 8;               // k base for this lane

    // Banded weight fragment: band_f[q] = g[kB+q - fi] (zero outside 0..10).
    f16x8 band_f;
    #pragma unroll
    for (int q = 0; q < 8; ++q) {
        float wq = 0.f;
        #pragma unroll
        for (int j = 0; j <= 10; ++j)
            wq = (kB + q - fi == j) ? g[j] : wq;
        band_f[q] = (_Float16)wq;
    }

    float acc = 0.f;
    const f32x4 z = {0.f, 0.f, 0.f, 0.f};

    // Hoisted V-load indices: row r0+kB+q (clamped; k>=26 weights are zero so
    // clamped garbage contributes 0), col base wv*64 + fi.
    int idx[8];
    #pragma unroll
    for (int q = 0; q < 8; ++q) {
        const int rr = min(r0 + kB + q, IMG - 1);
        idx[q] = rr * IMG + wv * 64 + fi;
    }

#define VLOAD(T, XS, YS) \
    { _Pragma("unroll") \
      for (int q = 0; q < 8; ++q) { \
          XS[q] = ip[idx[q] + 16*(T)]; \
          YS[q] = tp[idx[q] + 16*(T)]; \
      } }

#define VSTORE(F, D) \
    { H4u u_; \
      u_.p[0] = __builtin_amdgcn_cvt_pkrtz((D)[0], (D)[1]); \
      u_.p[1] = __builtin_amdgcn_cvt_pkrtz((D)[2], (D)[3]); \
      *reinterpret_cast<h4*>(&vlds[F][fi][cb_]) = u_.v; }

#define VPROC(T, XS, YS) \
    { H8u ux, uy; \
      ux.p[0] = __builtin_amdgcn_cvt_pkrtz(XS[0], XS[1]); \
      ux.p[1] = __builtin_amdgcn_cvt_pkrtz(XS[2], XS[3]); \
      ux.p[2] = __builtin_amdgcn_cvt_pkrtz(XS[4], XS[5]); \
      ux.p[3] = __builtin_amdgcn_cvt_pkrtz(XS[6], XS[7]); \
      uy.p[0] = __builtin_amdgcn_cvt_pkrtz(YS[0], YS[1]); \
      uy.p[1] = __builtin_amdgcn_cvt_pkrtz(YS[2], YS[3]); \
      uy.p[2] = __builtin_amdgcn_cvt_pkrtz(YS[4], YS[5]); \
      uy.p[3] = __builtin_amdgcn_cvt_pkrtz(YS[6], YS[7]); \
      f16x8 fX = ux.v, fY = uy.v; \
      f16x8 fS = fX + fY, fD = fX - fY;      /* v_pk_add/sub_f16 */ \
      f16x8 fP = fS * fS, fM = fD * fD;      /* v_pk_mul_f16 */ \
      f32x4 dX = __builtin_amdgcn_mfma_f32_16x16x32_f16(fX, band_f, z, 0, 0, 0); \
      f32x4 dY = __builtin_amdgcn_mfma_f32_16x16x32_f16(fY, band_f, z, 0, 0, 0); \
      f32x4 dP = __builtin_amdgcn_mfma_f32_16x16x32_f16(fP, band_f, z, 0, 0, 0); \
      f32x4 dM = __builtin_amdgcn_mfma_f32_16x16x32_f16(fM, band_f, z, 0, 0, 0); \
      const int cb_ = (wv*4 + (T))*16 + kg*4; \
      VSTORE(0, dX) VSTORE(1, dY) VSTORE(2, dP) VSTORE(3, dM) }

    float xA[8], yA[8], xB[8], yB[8];
    VLOAD(0, xA, yA)
    VLOAD(1, xB, yB)     // depth-2 prefetch
    VPROC(0, xA, yA)
    VLOAD(2, xA, yA)
    VPROC(1, xB, yB)
    VLOAD(3, xB, yB)
    VPROC(2, xA, yA)
    VPROC(3, xB, yB)

    __syncthreads();     // the only inter-phase barrier

    // ---- H phase: A-frag = vlds[f][fi][c0+kB..+7] (one b128/field) ----
#define HPROC(T) \
    { const int c0_ = (wv*4 + (T))*16; \
      const int kb_ = min(c0_ + kB, IMG - 8); \
      f16x8 aX = *reinterpret_cast<const f16x8*>(&vlds[0][fi][kb_]); \
      f16x8 aY = *reinterpret_cast<const f16x8*>(&vlds[1][fi][kb_]); \
      f16x8 aP = *reinterpret_cast<const f16x8*>(&vlds[2][fi][kb_]); \
      f16x8 aM = *reinterpret_cast<const f16x8*>(&vlds[3][fi][kb_]); \
      f32x4 dX = __builtin_amdgcn_mfma_f32_16x16x32_f16(aX, band_f, z, 0, 0, 0); \
      f32x4 dY = __builtin_amdgcn_mfma_f32_16x16x32_f16(aY, band_f, z, 0, 0, 0); \
      f32x4 dP = __builtin_amdgcn_mfma_f32_16x16x32_f16(aP, band_f, z, 0, 0, 0); \
      f32x4 dM = __builtin_amdgcn_mfma_f32_16x16x32_f16(aM, band_f, z, 0, 0, 0); \
      const int oc = c0_ + fi; \
      if (oc < OUT_N) { \
          if (!edge) { \
              v2f mx0 = {dX[0], dX[1]}, my0 = {dY[0], dY[1]}; \
              v2f P0  = {dP[0], dP[1]}, M0  = {dM[0], dM[1]}; \
              v2f mx1 = {dX[2], dX[3]}, my1 = {dY[2], dY[3]}; \
              v2f P1  = {dP[2], dP[3]}, M1  = {dM[2], dM[3]}; \
              acc += ssim_px2(mx0, my0, P0, M0); \
              acc += ssim_px2(mx1, my1, P1, M1); \
          } else { \
              _Pragma("unroll") \
              for (int m = 0; m < 4; ++m) { \
                  const int oy = r0 + kg*4 + m; \
                  if (oy < OUT_N) \
                      acc += ssim_px(dX[m], dY[m], dP[m], dM[m]); \
              } \
          } } }

    HPROC(0) HPROC(1) HPROC(2) HPROC(3)

    // block reduction: wave shuffle, then 8 wave-partials through LDS
    #pragma unroll
    for (int off = 32; off > 0; off >>= 1)
        acc += __shfl_down(acc, off, 64);
    if (lane == 0) red[wv] = acc;
    __syncthreads();
    if (tid == 0) {
        float t = 0.f;
        #pragma unroll
        for (int i = 0; i < 8; ++i) t += red[i];
        partial[plane * NBAND + band] = t;
    }
}

// Deterministic final reduction: fixed traversal, double accumulation.
__global__ __launch_bounds__(256) void ssim_final(
    const float* __restrict__ partial, int n, float* __restrict__ out)
{
    __shared__ double red[256];
    double s = 0.0;
    for (int i = threadIdx.x; i < n; i += 256) s += (double)partial[i];
    red[threadIdx.x] = s;
    __syncthreads();
    for (int off = 128; off > 0; off >>= 1) {
        if (threadIdx.x < off) red[threadIdx.x] += red[threadIdx.x + off];
        __syncthreads();
    }
    if (threadIdx.x == 0) out[0] = (float)(1.0 - red[0] / (double)NPLANE);
}

extern "C" void kernel_launch(void* const* d_in, const int* in_sizes, int n_in,
                              void* d_out, int out_size, void* d_ws, size_t ws_size,
                              hipStream_t stream) {
    const float* in  = (const float*)d_in[0];
    const float* tgt = (const float*)d_in[1];
    const float* wt  = (const float*)d_in[2];
    float* out  = (float*)d_out;
    float* part = (float*)d_ws;

    dim3 grid(NBAND, NPLANE);    // 32 bands x 48 planes = 1536 blocks
    ssim_band<<<grid, 512, 0, stream>>>(in, tgt, wt, part);
    ssim_final<<<1, 256, 0, stream>>>(part, NBAND * NPLANE, out);
}

// Round 21
// 39.313 us; speedup vs baseline: 2.0587x; 1.0018x over previous
//
#include <hip/hip_runtime.h>

typedef __attribute__((ext_vector_type(8))) _Float16 f16x8;
typedef __attribute__((ext_vector_type(4))) float f32x4;
typedef __attribute__((ext_vector_type(4))) _Float16 h4;
typedef __attribute__((ext_vector_type(2))) __fp16 hw2;
typedef __attribute__((ext_vector_type(2))) float v2f;

#define IMG 512
#define OUT_N 502
#define NPLANE 48
#define NBAND 32             // 16 output rows per band
#define VP 520               // LDS pitch (fp16): 512 + 8 pad (keeps b128 align)
#define C1c 0.0001f
#define C2c 0.0004f

union H8u { hw2 p[4]; f16x8 v; };
union H4u { hw2 p[2]; h4 v; };

// scalar ssim (edge band only)
__device__ __forceinline__ float ssim_px(float mx, float my, float P, float M) {
    float A = mx*mx, B = my*my, mxy = mx*my;
    float sumsq = 0.5f*(P+M) - A - B;
    float sxy   = 0.25f*(P-M) - mxy;
    float num = (2.f*mxy + C1c) * (2.f*sxy + C2c);
    float den = (A + B + C1c) * (sumsq + C2c);
    return num * __builtin_amdgcn_rcpf(den);
}

// packed-pair ssim: v_pk_*_f32 for the elementwise chain, scalar rcp x2
__device__ __forceinline__ float ssim_px2(v2f mx, v2f my, v2f P, v2f M) {
    v2f A = mx*mx, B = my*my, mxy = mx*my;
    v2f sumsq = 0.5f*(P+M) - A - B;
    v2f sxy   = 0.25f*(P-M) - mxy;
    v2f num = (2.f*mxy + C1c) * (2.f*sxy + C2c);
    v2f den = (A + B + C1c) * (sumsq + C2c);
    return num.x * __builtin_amdgcn_rcpf(den.x)
         + num.y * __builtin_amdgcn_rcpf(den.y);
}

// Block = one 16-row output band, 512 threads (8 waves). Both blurs are banded
// matmuls on the matrix pipe (layouts verified absmax 0.0 in R19):
//   V: D = Data(16x32) x Band(32x16) -> lane holds out-row fi, 4 consecutive
//      cols -> one packed ds_write_b64 per field.
//   H: D = Vdata(16x32) x Band(32x16), A-frag = one ds_read_b128 per field.
// R21 delta: V-phase loads batched to FULL depth (all 4 tiles issued before
// any consume) -- one load latency for the whole phase instead of a depth-2
// chain. +32 VGPR, under the (512,2) cap of 128; LDS still binds 2 blocks/CU.
__global__ __launch_bounds__(512, 2) void ssim_band(
    const float* __restrict__ in, const float* __restrict__ tgt,
    const float* __restrict__ w, float* __restrict__ partial)
{
    __shared__ __attribute__((aligned(16))) _Float16 vlds[4][16][VP];
    __shared__ float g1s[16];
    __shared__ float red[8];

    const int tid   = threadIdx.x;
    const int lane  = tid & 63;
    const int wv    = tid >> 6;          // wave id 0..7
    const int band  = blockIdx.x;
    const int plane = blockIdx.y;
    const int r0 = band * 16;
    const bool edge = (r0 + 16 > OUT_N);          // block-uniform (band 31)
    const float* __restrict__ ip = in  + (size_t)plane * (IMG*IMG);
    const float* __restrict__ tp = tgt + (size_t)plane * (IMG*IMG);

    // 1D factor = row sums of the 2D kernel (exact: w2d = outer(g,g), sum = 1)
    if (tid < 11) {
        float s = 0.f;
        #pragma unroll
        for (int j = 0; j < 11; ++j) s += w[tid*11 + j];
        g1s[tid] = s;
    }
    __syncthreads();
    float g[11];
    #pragma unroll
    for (int j = 0; j < 11; ++j)
        g[j] = __int_as_float(__builtin_amdgcn_readfirstlane(__float_as_int(g1s[j])));

    const int fi = lane & 15;            // A-row / B-col / D-col index
    const int kg = lane >> 4;            // k-group (0..3)
    const int kB = kg * 8;               // k base for this lane

    // Banded weight fragment: band_f[q] = g[kB+q - fi] (zero outside 0..10).
    f16x8 band_f;
    #pragma unroll
    for (int q = 0; q < 8; ++q) {
        float wq = 0.f;
        #pragma unroll
        for (int j = 0; j <= 10; ++j)
            wq = (kB + q - fi == j) ? g[j] : wq;
        band_f[q] = (_Float16)wq;
    }

    float acc = 0.f;
    const f32x4 z = {0.f, 0.f, 0.f, 0.f};

    // Hoisted V-load indices: row r0+kB+q (clamped; k>=26 weights are zero so
    // clamped garbage contributes 0), col base wv*64 + fi.
    int idx[8];
    #pragma unroll
    for (int q = 0; q < 8; ++q) {
        const int rr = min(r0 + kB + q, IMG - 1);
        idx[q] = rr * IMG + wv * 64 + fi;
    }

#define VLOAD(T, XS, YS) \
    { _Pragma("unroll") \
      for (int q = 0; q < 8; ++q) { \
          XS[q] = ip[idx[q] + 16*(T)]; \
          YS[q] = tp[idx[q] + 16*(T)]; \
      } }

#define VSTORE(F, D) \
    { H4u u_; \
      u_.p[0] = __builtin_amdgcn_cvt_pkrtz((D)[0], (D)[1]); \
      u_.p[1] = __builtin_amdgcn_cvt_pkrtz((D)[2], (D)[3]); \
      *reinterpret_cast<h4*>(&vlds[F][fi][cb_]) = u_.v; }

#define VPROC(T, XS, YS) \
    { H8u ux, uy; \
      ux.p[0] = __builtin_amdgcn_cvt_pkrtz(XS[0], XS[1]); \
      ux.p[1] = __builtin_amdgcn_cvt_pkrtz(XS[2], XS[3]); \
      ux.p[2] = __builtin_amdgcn_cvt_pkrtz(XS[4], XS[5]); \
      ux.p[3] = __builtin_amdgcn_cvt_pkrtz(XS[6], XS[7]); \
      uy.p[0] = __builtin_amdgcn_cvt_pkrtz(YS[0], YS[1]); \
      uy.p[1] = __builtin_amdgcn_cvt_pkrtz(YS[2], YS[3]); \
      uy.p[2] = __builtin_amdgcn_cvt_pkrtz(YS[4], YS[5]); \
      uy.p[3] = __builtin_amdgcn_cvt_pkrtz(YS[6], YS[7]); \
      f16x8 fX = ux.v, fY = uy.v; \
      f16x8 fS = fX + fY, fD = fX - fY;      /* v_pk_add/sub_f16 */ \
      f16x8 fP = fS * fS, fM = fD * fD;      /* v_pk_mul_f16 */ \
      f32x4 dX = __builtin_amdgcn_mfma_f32_16x16x32_f16(fX, band_f, z, 0, 0, 0); \
      f32x4 dY = __builtin_amdgcn_mfma_f32_16x16x32_f16(fY, band_f, z, 0, 0, 0); \
      f32x4 dP = __builtin_amdgcn_mfma_f32_16x16x32_f16(fP, band_f, z, 0, 0, 0); \
      f32x4 dM = __builtin_amdgcn_mfma_f32_16x16x32_f16(fM, band_f, z, 0, 0, 0); \
      const int cb_ = (wv*4 + (T))*16 + kg*4; \
      VSTORE(0, dX) VSTORE(1, dY) VSTORE(2, dP) VSTORE(3, dM) }

    // Batch-issue ALL V-phase loads (4 tiles, 64 VGPR), then consume.
    float x0[8], y0[8], x1[8], y1[8], x2[8], y2[8], x3[8], y3[8];
    VLOAD(0, x0, y0)
    VLOAD(1, x1, y1)
    VLOAD(2, x2, y2)
    VLOAD(3, x3, y3)
    VPROC(0, x0, y0)
    VPROC(1, x1, y1)
    VPROC(2, x2, y2)
    VPROC(3, x3, y3)

    __syncthreads();     // the only inter-phase barrier

    // ---- H phase: A-frag = vlds[f][fi][c0+kB..+7] (one b128/field) ----
#define HPROC(T) \
    { const int c0_ = (wv*4 + (T))*16; \
      const int kb_ = min(c0_ + kB, IMG - 8); \
      f16x8 aX = *reinterpret_cast<const f16x8*>(&vlds[0][fi][kb_]); \
      f16x8 aY = *reinterpret_cast<const f16x8*>(&vlds[1][fi][kb_]); \
      f16x8 aP = *reinterpret_cast<const f16x8*>(&vlds[2][fi][kb_]); \
      f16x8 aM = *reinterpret_cast<const f16x8*>(&vlds[3][fi][kb_]); \
      f32x4 dX = __builtin_amdgcn_mfma_f32_16x16x32_f16(aX, band_f, z, 0, 0, 0); \
      f32x4 dY = __builtin_amdgcn_mfma_f32_16x16x32_f16(aY, band_f, z, 0, 0, 0); \
      f32x4 dP = __builtin_amdgcn_mfma_f32_16x16x32_f16(aP, band_f, z, 0, 0, 0); \
      f32x4 dM = __builtin_amdgcn_mfma_f32_16x16x32_f16(aM, band_f, z, 0, 0, 0); \
      const int oc = c0_ + fi; \
      if (oc < OUT_N) { \
          if (!edge) { \
              v2f mx0 = {dX[0], dX[1]}, my0 = {dY[0], dY[1]}; \
              v2f P0  = {dP[0], dP[1]}, M0  = {dM[0], dM[1]}; \
              v2f mx1 = {dX[2], dX[3]}, my1 = {dY[2], dY[3]}; \
              v2f P1  = {dP[2], dP[3]}, M1  = {dM[2], dM[3]}; \
              acc += ssim_px2(mx0, my0, P0, M0); \
              acc += ssim_px2(mx1, my1, P1, M1); \
          } else { \
              _Pragma("unroll") \
              for (int m = 0; m < 4; ++m) { \
                  const int oy = r0 + kg*4 + m; \
                  if (oy < OUT_N) \
                      acc += ssim_px(dX[m], dY[m], dP[m], dM[m]); \
              } \
          } } }

    HPROC(0) HPROC(1) HPROC(2) HPROC(3)

    // block reduction: wave shuffle, then 8 wave-partials through LDS
    #pragma unroll
    for (int off = 32; off > 0; off >>= 1)
        acc += __shfl_down(acc, off, 64);
    if (lane == 0) red[wv] = acc;
    __syncthreads();
    if (tid == 0) {
        float t = 0.f;
        #pragma unroll
        for (int i = 0; i < 8; ++i) t += red[i];
        partial[plane * NBAND + band] = t;
    }
}

// Deterministic final reduction: fixed traversal, double accumulation.
__global__ __launch_bounds__(256) void ssim_final(
    const float* __restrict__ partial, int n, float* __restrict__ out)
{
    __shared__ double red[256];
    double s = 0.0;
    for (int i = threadIdx.x; i < n; i += 256) s += (double)partial[i];
    red[threadIdx.x] = s;
    __syncthreads();
    for (int off = 128; off > 0; off >>= 1) {
        if (threadIdx.x < off) red[threadIdx.x] += red[threadIdx.x + off];
        __syncthreads();
    }
    if (threadIdx.x == 0) out[0] = (float)(1.0 - red[0] / (double)NPLANE);
}

extern "C" void kernel_launch(void* const* d_in, const int* in_sizes, int n_in,
                              void* d_out, int out_size, void* d_ws, size_t ws_size,
                              hipStream_t stream) {
    const float* in  = (const float*)d_in[0];
    const float* tgt = (const float*)d_in[1];
    const float* wt  = (const float*)d_in[2];
    float* out  = (float*)d_out;
    float* part = (float*)d_ws;

    dim3 grid(NBAND, NPLANE);    // 32 bands x 48 planes = 1536 blocks
    ssim_band<<<grid, 512, 0, stream>>>(in, tgt, wt, part);
    ssim_final<<<1, 256, 0, stream>>>(part, NBAND * NPLANE, out);
}